// Round 4
// baseline (187.291 us; speedup 1.0000x reference)
//
#include <hip/hip_runtime.h>

// ToBEVReduction: sorted-unique over 27-bit packed coords + segment mean.
// bitmap -> hierarchical popcount scan (fused with sorted enumeration of the
// unique coords) -> per-element rank (k_seg, batches all random small reads +
// count atomics) -> PURE scatter copy (seq reads, random full-row writes,
// zero bookkeeping). Duplicate segments (~0.15%) tracked via a 50KB segment
// bitmap; fixed up by zero + rescan-accumulate micro-kernels.

#define NWORDS      (1u << 22)              // 2^27 bits / 32
#define SCAN_BLOCKS 1024
#define WPB         (NWORDS / SCAN_BLOCKS)  // 4096 words per block
#define WPT         (WPB / 256)             // 16 words per thread

typedef float f32x4 __attribute__((ext_vector_type(4)));
typedef unsigned u32;

__global__ void k_build(const int4* __restrict__ coords, u32* __restrict__ bitmap,
                        u32* __restrict__ keys, float* __restrict__ cnt,
                        u32* __restrict__ dupBits, u32* __restrict__ ctrs, int N) {
    int i = blockIdx.x * blockDim.x + threadIdx.x;
    if (i < 16384) dupBits[i] = 0u;          // 64KB dup-segment bitmap
    if (i == 0) ctrs[1] = 0u;
    if (i >= N) return;
    int4 c = coords[i];  // non-Z dims are cols 0,2,3 (Z_DIM=1)
    u32 key = ((u32)c.x << 18) | ((u32)c.z << 9) | (u32)c.w;
    keys[i] = key;
    cnt[i] = 0.0f;
    atomicOr(&bitmap[key >> 5], 1u << (key & 31u));
}

__global__ void k_scan1(const u32* __restrict__ bitmap, u32* __restrict__ blockSums) {
    __shared__ u32 sd[256];
    const uint4* bm = (const uint4*)(bitmap + (size_t)blockIdx.x * WPB + (size_t)threadIdx.x * WPT);
    u32 s = 0;
#pragma unroll
    for (int k = 0; k < WPT / 4; ++k) {
        uint4 v = bm[k];
        s += __popc(v.x) + __popc(v.y) + __popc(v.z) + __popc(v.w);
    }
    sd[threadIdx.x] = s;
    __syncthreads();
    for (int off = 128; off > 0; off >>= 1) {
        if ((int)threadIdx.x < off) sd[threadIdx.x] += sd[threadIdx.x + off];
        __syncthreads();
    }
    if (threadIdx.x == 0) blockSums[blockIdx.x] = sd[0];
}

__global__ void k_scan2(const u32* __restrict__ blockSums,
                        u32* __restrict__ blockOffsets,
                        u32* __restrict__ totalM) {
    __shared__ u32 sd[SCAN_BLOCKS];
    int t = threadIdx.x;
    u32 v = blockSums[t];
    sd[t] = v;
    __syncthreads();
    for (int off = 1; off < SCAN_BLOCKS; off <<= 1) {
        u32 add = (t >= off) ? sd[t - off] : 0u;
        __syncthreads();
        sd[t] += add;
        __syncthreads();
    }
    blockOffsets[t] = sd[t] - v;  // exclusive
    if (t == SCAN_BLOCKS - 1) totalM[0] = sd[t];  // unique count M
}

// Fused: per-word {rank offset, bits} pairs AND sorted-unique coords output.
__global__ void k_scan3enum(const u32* __restrict__ bitmap,
                            const u32* __restrict__ blockOffsets,
                            uint2* __restrict__ pairs,
                            float4* __restrict__ outc) {
    __shared__ u32 sd[256];
    size_t base = (size_t)blockIdx.x * WPB + (size_t)threadIdx.x * WPT;
    const uint4* bm = (const uint4*)(bitmap + base);
    u32 w[WPT];
    u32 s = 0;
#pragma unroll
    for (int k = 0; k < WPT / 4; ++k) {
        uint4 v = bm[k];
        w[k * 4 + 0] = v.x; w[k * 4 + 1] = v.y; w[k * 4 + 2] = v.z; w[k * 4 + 3] = v.w;
        s += __popc(v.x) + __popc(v.y) + __popc(v.z) + __popc(v.w);
    }
    int t = threadIdx.x;
    sd[t] = s;
    __syncthreads();
    for (int off = 1; off < 256; off <<= 1) {
        u32 add = (t >= off) ? sd[t - off] : 0u;
        __syncthreads();
        sd[t] += add;
        __syncthreads();
    }
    u32 run = blockOffsets[blockIdx.x] + sd[t] - s;  // exclusive prefix
#pragma unroll
    for (int k = 0; k < WPT; ++k) {
        u32 bits = w[k];
        pairs[base + k] = make_uint2(run, bits);
        while (bits) {
            int b = __ffs(bits) - 1;
            u32 key = ((u32)(base + k) << 5) | (u32)b;
            outc[run] = make_float4((float)(key >> 18), 0.f,
                                    (float)((key >> 9) & 511u), (float)(key & 511u));
            ++run;
            bits &= bits - 1u;
        }
    }
}

// Rank + count + dup registration. All random small accesses batched here,
// off the heavy kernel's critical path.
__global__ void k_seg(const u32* __restrict__ keys, const uint2* __restrict__ pairs,
                      float* __restrict__ cnt, u32* __restrict__ seg,
                      u32* __restrict__ dupSeg, u32* __restrict__ dupBits,
                      u32* __restrict__ ctrs, int N) {
    int i = blockIdx.x * blockDim.x + threadIdx.x;
    if (i >= N) return;
    u32 key = keys[i];
    uint2 p = pairs[key >> 5];
    u32 s = p.x + __popc(p.y & ((1u << (key & 31u)) - 1u));
    seg[i] = s;
    float old = atomicAdd(&cnt[s], 1.0f);
    if (old == 1.0f) {  // exactly-second arrival registers the dup segment once
        u32 ds = atomicAdd(&ctrs[1], 1u);
        dupSeg[ds] = s;
        atomicOr(&dupBits[s >> 5], 1u << (s & 31u));
    }
}

// Pure permutation copy: sequential reads, random full-512B-row writes.
__global__ void __launch_bounds__(256) k_scatter(
        const f32x4* __restrict__ fin, const u32* __restrict__ seg,
        f32x4* __restrict__ fout, int N) {
    int gid = blockIdx.x * blockDim.x + threadIdx.x;
    int elem = gid >> 5;  // 32 threads (16B each) per 128-float row
    if (elem >= N) return;
    int c4 = gid & 31;
    u32 s = seg[elem];  // 32 lanes same word -> broadcast; seq across waves
    f32x4 v = __builtin_nontemporal_load(&fin[(size_t)elem * 32 + c4]);
    __builtin_nontemporal_store(v, &fout[(size_t)s * 32 + c4]);
}

// Zero the ~600 dup rows (garbage race winners) and write pad rows/coords.
__global__ void k_fix1(const u32* __restrict__ dupSeg, const u32* __restrict__ ctrs,
                       const u32* __restrict__ totalM,
                       f32x4* __restrict__ fout, float4* __restrict__ outc, int N) {
    u32 nds = ctrs[1];
    u32 M = totalM[0];
    u32 npad = (u32)N - M;
    u32 total = nds + npad;
    int gid = blockIdx.x * blockDim.x + threadIdx.x;
    int c4 = gid & 31;
    u32 stride = (gridDim.x * blockDim.x) >> 5;
    f32x4 z = {0.f, 0.f, 0.f, 0.f};
    for (u32 r = (u32)(gid >> 5); r < total; r += stride) {
        bool pad = (r >= nds);
        u32 row = pad ? (M + r - nds) : dupSeg[r];
        fout[(size_t)row * 32 + c4] = z;
        if (pad && c4 == 0) outc[row] = make_float4(-1.f, 0.f, 511.f, 511.f);
    }
}

// Accumulate mean contributions for dup segments: rescan seg[] (seq, 1.6MB)
// with an L2-resident dup bitmap test; ~1200 hits do the atomic row add.
__global__ void k_fix2(const f32x4* __restrict__ fin, const u32* __restrict__ seg,
                       const float* __restrict__ cnt, const u32* __restrict__ dupBits,
                       f32x4* __restrict__ fout, int N) {
    int i = blockIdx.x * blockDim.x + threadIdx.x;
    if (i >= N) return;
    u32 s = seg[i];
    if (!(dupBits[s >> 5] & (1u << (s & 31u)))) return;  // ~99.7% exit
    float inv = 1.0f / cnt[s];
    const f32x4* src = &fin[(size_t)i * 32];
    float* dst = (float*)&fout[(size_t)s * 32];
#pragma unroll 4
    for (int c = 0; c < 32; ++c) {
        f32x4 v = src[c];
        atomicAdd(dst + c * 4 + 0, v.x * inv);
        atomicAdd(dst + c * 4 + 1, v.y * inv);
        atomicAdd(dst + c * 4 + 2, v.z * inv);
        atomicAdd(dst + c * 4 + 3, v.w * inv);
    }
}

extern "C" void kernel_launch(void* const* d_in, const int* in_sizes, int n_in,
                              void* d_out, int out_size, void* d_ws, size_t ws_size,
                              hipStream_t stream) {
    const f32x4* feat_in = (const f32x4*)d_in[0];
    const int4* coords = (const int4*)d_in[1];
    int N = in_sizes[1] / 4;  // 400000

    float* out = (float*)d_out;
    f32x4* out_feat = (f32x4*)out;                            // N*128 floats
    float4* out_coords = (float4*)(out + (size_t)N * 128);    // N*4 floats
    float* out_cnt = out + (size_t)N * 132;                   // N floats

    // Scratch in d_ws (~52 MB; ws poison fill shows ws_size ~850 MB).
    // 16B-aligned arrays first (uint4 reads in scan kernels).
    u32* bitmap = (u32*)d_ws;                          // NWORDS (16 MB)
    uint2* pairs = (uint2*)(bitmap + NWORDS);          // NWORDS uint2 (32 MB)
    u32* keys = (u32*)(pairs + NWORDS);                // N
    u32* seg = keys + N;                               // N
    u32* dupSeg = seg + N;                             // 65536
    u32* dupBits = dupSeg + 65536;                     // 16384 (64 KB)
    u32* blockSums = dupBits + 16384;                  // SCAN_BLOCKS
    u32* blockOffsets = blockSums + SCAN_BLOCKS;       // SCAN_BLOCKS
    u32* totalM = blockOffsets + SCAN_BLOCKS;          // 1
    u32* ctrs = totalM + 1;                            // 8

    int nb = (N + 255) / 256;

    hipMemsetAsync(bitmap, 0, (size_t)NWORDS * 4, stream);

    k_build<<<nb, 256, 0, stream>>>(coords, bitmap, keys, out_cnt, dupBits, ctrs, N);
    k_scan1<<<SCAN_BLOCKS, 256, 0, stream>>>(bitmap, blockSums);
    k_scan2<<<1, SCAN_BLOCKS, 0, stream>>>(blockSums, blockOffsets, totalM);
    k_scan3enum<<<SCAN_BLOCKS, 256, 0, stream>>>(bitmap, blockOffsets, pairs, out_coords);
    k_seg<<<nb, 256, 0, stream>>>(keys, pairs, out_cnt, seg, dupSeg, dupBits, ctrs, N);
    k_scatter<<<(int)(((size_t)N * 32 + 255) / 256), 256, 0, stream>>>(
        feat_in, seg, out_feat, N);
    k_fix1<<<256, 256, 0, stream>>>(dupSeg, ctrs, totalM, out_feat, out_coords, N);
    k_fix2<<<nb, 256, 0, stream>>>(feat_in, seg, out_cnt, dupBits, out_feat, N);
}